// Round 11
// baseline (188.419 us; speedup 1.0000x reference)
//
#include <hip/hip_runtime.h>
#include <hip/hip_bf16.h>

// Shapes: B=8, Q=1, T=2048, H=512, V=32000
#define Hdim 512
#define Bdim 8
#define Tdim 2048
#define Vdim 32000
#define OUTW (Vdim + Tdim)        // 34048
#define DEC_TILES (Vdim / 128)    // 250
#define REP_TILES ((Bdim * Tdim) / 128)  // 128
#define NTILES (DEC_TILES + REP_TILES)   // 378

typedef __attribute__((ext_vector_type(8))) short short8;
typedef __attribute__((ext_vector_type(16))) float f32x16;

__device__ __forceinline__ unsigned packbf2(float a, float b) {
    __hip_bfloat162 h = __float22bfloat162_rn(make_float2(a, b));  // a -> low 16
    union { __hip_bfloat162 h; unsigned u; } c; c.h = h;
    return c.u;
}

union U8 { unsigned u[4]; short8 s; };
__device__ __forceinline__ short8 cvt8(const float4 f0, const float4 f1) {
    U8 r;
    r.u[0] = packbf2(f0.x, f0.y); r.u[1] = packbf2(f0.z, f0.w);
    r.u[2] = packbf2(f1.x, f1.y); r.u[3] = packbf2(f1.z, f1.w);
    return r.s;
}

// ---------------- prep: w1t -> bf16 [n][k] + qp + out-init (r1-verified) ------
#define WT_BLOCKS 128                  // 512x512 elems, 8 per thread
#define QP_BLOCKS (Bdim * Hdim / 4)    // 1024 blocks of 4 waves
#define INIT_BLOCKS (Bdim * OUTW / 4 / 256)   // 266: float4-init of out

__global__ __launch_bounds__(256) void prep_kernel(
    const float* __restrict__ w1, const float* __restrict__ x,
    const float* __restrict__ b1, const float* __restrict__ mask,
    unsigned short* __restrict__ wt, float* __restrict__ qp,
    float* __restrict__ out)
{
    const int bid = blockIdx.x;
    if (bid < WT_BLOCKS) {
        // wt[n][kk] = bf16(w1[n*1024 + 512 + kk])
        const int i = bid * 256 + threadIdx.x;   // 8-elem group index
        const int n = i >> 6;
        const int kk = (i & 63) * 8;
        const float4* s = (const float4*)(w1 + (size_t)n * 1024 + 512 + kk);
        const float4 v0 = s[0], v1 = s[1];
        uint4 o;
        o.x = packbf2(v0.x, v0.y); o.y = packbf2(v0.z, v0.w);
        o.z = packbf2(v1.x, v1.y); o.w = packbf2(v1.z, v1.w);
        ((uint4*)wt)[i] = o;
    } else if (bid < WT_BLOCKS + QP_BLOCKS) {
        // qp[b,k] = x[b,:].w1q[k,:] + b1[k], one wave per (b,k)
        const int widx = (bid - WT_BLOCKS) * 4 + (threadIdx.x >> 6);
        const int lane = threadIdx.x & 63;
        const int b = widx >> 9, k = widx & 511;
        const float4* xr = (const float4*)(x + b * Hdim);
        const float4* wr = (const float4*)(w1 + (size_t)k * 1024);
        float4 x0 = xr[lane * 2], x1 = xr[lane * 2 + 1];
        float4 w0 = wr[lane * 2], w1v = wr[lane * 2 + 1];
        float s = x0.x * w0.x + x0.y * w0.y + x0.z * w0.z + x0.w * w0.w
                + x1.x * w1v.x + x1.y * w1v.y + x1.z * w1v.z + x1.w * w1v.w;
#pragma unroll
        for (int off = 32; off > 0; off >>= 1) s += __shfl_down(s, off);
        if (lane == 0) qp[b * Hdim + k] = s + b1[k];
    } else {
        // out init: dec region = 0, rep region = -1000*(1-mask)  (gemm atomicAdds partials)
        const int idx4 = (bid - WT_BLOCKS - QP_BLOCKS) * 256 + threadIdx.x;  // float4 idx
        const int b = idx4 / (OUTW / 4);
        const int c4 = (idx4 - b * (OUTW / 4)) * 4;     // col within row, mult of 4
        float4 v;
        if (c4 < Vdim) {
            v = make_float4(0.f, 0.f, 0.f, 0.f);
        } else {
            const int t = c4 - Vdim;
            const float4 mv = *(const float4*)(mask + b * Tdim + t);
            v = make_float4(-1000.f * (1.f - mv.x), -1000.f * (1.f - mv.y),
                            -1000.f * (1.f - mv.z), -1000.f * (1.f - mv.w));
        }
        ((float4*)out)[idx4] = v;
    }
}

// ---------------- fused MFMA GEMM + atomic epilogue -> out --------------------
// Round-11: r10 (173.6us, gemm 73.9) with the gemm's LDS/VALU cost attacked:
// A is now BF16 in LDS, converted once at staging (reg-stage 4xfloat4 ->
// 8 packbf2 -> 2 ds_write_b128), not per-use in the inner loop.  Both A and W
// use [2][32][128]-short layout: 256B rows, 16 x 16B slots, XOR slot^(row&15)
// -> 2-way bank access (free, m136).  Inner loop is pure {8 ds_read_b128 +
// 16 MFMA}: LDS reads -33%, writes 24->16KB/step, cvt off the MFMA chain,
// LDS 48->32KB.  Sync semantics = r5's verified single-__syncthreads pattern
// (compiler-managed waits only; CVT's data-dep waits just the 4 rA loads,
// W-glds drain at the barrier with latency hidden under COMPUTE).
// (r7 retried this and failed for two now-fixed reasons: (256,4) spill and
//  128B-row layout -> 4-way A-read conflicts.  Here: (256,3) + 256B rows.)
// Grid 1536 (48 groups x 32): mt = (b>>5)*8 + (b&7), chunk = (b>>3)&3 so the 4
// chunk-partners of one mt share blockIdx%8 (same XCD -> shared L2 A-tile).
// MFMA operands SWAPPED (mfma(W,A)): acc rows = n, acc cols = output row.
__global__ __launch_bounds__(256, 3) void gemm_kernel(
    const float* __restrict__ Adec,            // 32000 x 512 fp32 (original)
    const float* __restrict__ Atgt,            // 16384 x 512 fp32 (original)
    const unsigned short* __restrict__ Wt,     // 512 x 512 bf16 (w1t [n][k])
    const float* __restrict__ qp,              // 8 x 512 fp32
    const float* __restrict__ w2,              // 512 fp32
    const float* __restrict__ mask,            // 8 x 2048 fp32
    float* __restrict__ out)                   // 8 x 34048 fp32 (pre-initialized)
{
    // A/W: bf16 tile 128 x 32k, packed 4 rows/LDS-row: elem(r,k) at
    // [r&31][(r>>5)*32 + k]; slot s(r,k) = (r>>5)*4 + (k>>3), phys = s^(r&15).
    __shared__ union {
        struct { unsigned short A[2][32][128]; unsigned short W[2][32][128]; } g;  // 32 KB
        struct { float qT[8][128]; float w2c[128]; } e;
    } u;

    const int tid  = threadIdx.x;
    const int lane = tid & 63;
    const int w    = tid >> 6;

    const int b = blockIdx.x;
    const int mt = (b >> 5) * 8 + (b & 7);
    if (mt >= NTILES) return;
    const int chunk = (b >> 3) & 3;
    const int n0 = chunk << 7;
    const bool is_dec = (mt < DEC_TILES);
    const int m0 = (is_dec ? mt : mt - DEC_TILES) << 7;
    const float* __restrict__ Af = is_dec ? Adec : Atgt;

    // ---- A staging (reg -> cvt -> ds_write): thread = (row sr=tid>>1, k-half) ----
    const int sr  = tid >> 1;                      // tile row 0..127
    const float* gAr = Af + (size_t)(m0 + sr) * 512 + ((tid & 1) << 4);
    const int awr = sr & 31;                       // LDS row
    const int as0 = ((sr >> 5) << 2) + ((tid & 1) << 1);   // logical slot base
    const int ap0 = ((as0)     ^ (sr & 15)) << 3;  // short offsets (16B slots)
    const int ap1 = ((as0 + 1) ^ (sr & 15)) << 3;

    // ---- W staging via global_load_lds (pre-swizzled source, linear dest) ----
    // instr (w,j) covers LDS rows (w*2+j)*4 .. +4; lane l -> row rr, phys p=l&15;
    // logical s = p^(rr&15) -> source n = (s>>2)*32 + rr, k = (s&3)*8.
    const unsigned short* gWp[2];
#pragma unroll
    for (int j = 0; j < 2; ++j) {
        const int rr = (w * 2 + j) * 4 + (lane >> 4);
        const int s  = (lane & 15) ^ (rr & 15);
        gWp[j] = Wt + (size_t)(n0 + (s >> 2) * 32 + rr) * 512 + (s & 3) * 8;
    }

    float4 rA0, rA1, rA2, rA3;
#define GLOAD_A(kof) do {                                                     \
        rA0 = *(const float4*)(gAr + (kof));                                  \
        rA1 = *(const float4*)(gAr + (kof) + 4);                              \
        rA2 = *(const float4*)(gAr + (kof) + 8);                              \
        rA3 = *(const float4*)(gAr + (kof) + 12);                             \
    } while (0)
#define CVT_A(bb) do {                                                        \
        *(short8*)&u.g.A[bb][awr][ap0] = cvt8(rA0, rA1);                      \
        *(short8*)&u.g.A[bb][awr][ap1] = cvt8(rA2, rA3);                      \
    } while (0)
#define STAGE_W(bb, kof) do {                                                 \
        _Pragma("unroll")                                                     \
        for (int j = 0; j < 2; ++j)                                           \
            __builtin_amdgcn_global_load_lds(                                 \
                (const __attribute__((address_space(1))) unsigned int*)(gWp[j] + (kof)), \
                (__attribute__((address_space(3))) unsigned int*)(&u.g.W[bb][(w * 2 + j) * 4][0]), \
                16, 0, 0);                                                    \
    } while (0)

    f32x16 acc00, acc01, acc10, acc11;
#pragma unroll
    for (int i = 0; i < 16; ++i) { acc00[i] = 0.f; acc01[i] = 0.f; acc10[i] = 0.f; acc11[i] = 0.f; }

    const int wm  = (w & 1) << 6;     // output-row offset of this wave
    const int wn  = (w >> 1) << 6;    // n offset of this wave (within chunk)
    const int l31 = lane & 31;
    const int kh  = lane >> 5;
    const int rx15 = l31 & 15;
    const int ca  = wm >> 5;          // A packed-col base (0 or 2)
    const int cw  = wn >> 5;          // W packed-col base (0 or 2)

#define COMPUTE(bb) do {                                                      \
        _Pragma("unroll")                                                     \
        for (int s = 0; s < 2; ++s) {                                         \
            const int g = s * 2 + kh;                                         \
            const short8 a0 = *(const short8*)&u.g.A[bb][l31][(((ca)*4 + g) ^ rx15) << 3];     \
            const short8 a1 = *(const short8*)&u.g.A[bb][l31][(((ca+1)*4 + g) ^ rx15) << 3];   \
            const short8 b0 = *(const short8*)&u.g.W[bb][l31][(((cw)*4 + g) ^ rx15) << 3];     \
            const short8 b1 = *(const short8*)&u.g.W[bb][l31][(((cw+1)*4 + g) ^ rx15) << 3];   \
            acc00 = __builtin_amdgcn_mfma_f32_32x32x16_bf16(b0, a0, acc00, 0, 0, 0); \
            acc01 = __builtin_amdgcn_mfma_f32_32x32x16_bf16(b0, a1, acc01, 0, 0, 0); \
            acc10 = __builtin_amdgcn_mfma_f32_32x32x16_bf16(b1, a0, acc10, 0, 0, 0); \
            acc11 = __builtin_amdgcn_mfma_f32_32x32x16_bf16(b1, a1, acc11, 0, 0, 0); \
        }                                                                     \
    } while (0)

    // prologue: tile 0 -> regs -> buf0 (cvt waits rA dep); W glds -> buf0; publish.
    GLOAD_A(0);
    STAGE_W(0, 0);
    CVT_A(0);
    __syncthreads();    // drains W-glds(0) + ds_writes -> buf0 ready

    int cur = 0;
    for (int t = 0; t < 16; ++t) {
        if (t < 15) {
            GLOAD_A((t + 1) * 32);        // rA(t+1), hidden under COMPUTE
            STAGE_W(cur ^ 1, (t + 1) * 32);  // W(t+1) glds, hidden under COMPUTE
        }
        COMPUTE(cur);                     // tile t: pure ds_read+MFMA
        if (t < 15) CVT_A(cur ^ 1);       // waits rA(t+1) only (W glds younger)
        __syncthreads();                  // publish tile t+1; buf[cur] reads done
        cur ^= 1;
    }

#undef COMPUTE
#undef GLOAD_A
#undef CVT_A
#undef STAGE_W

    // ---------------- fused epilogue (atomic, r1/r10-verified pattern) ------
    // acc{X}{Y}[r]: n = wn + 32*X + ra2(r,kh), vrow = wm + 32*Y + l31
    // with r = run*4 + j: ra2 = j + 8*run + 4*kh  -> n runs are float4-contiguous.
    // (C/D layout verified m74/m101: col=lane&31, row=(r&3)+8*(r>>2)+4*(lane>>5))
    {
        const int qb = tid >> 5;              // 0..7
        const int qn = (tid & 31) << 2;       // 0..124
        *(float4*)&u.e.qT[qb][qn] = *(const float4*)&qp[qb * Hdim + n0 + qn];
        if (tid < 32) *(float4*)&u.e.w2c[tid << 2] = *(const float4*)&w2[n0 + (tid << 2)];
    }
    __syncthreads();

    const int kh4 = kh << 2;

    // w2 fragments in regs (statically indexed -> 8 float4 = 32 VGPRs)
    float4 wvA[4], wvB[4];
#pragma unroll
    for (int run = 0; run < 4; ++run) {
        wvA[run] = *(const float4*)&u.e.w2c[wn + run * 8 + kh4];
        wvB[run] = *(const float4*)&u.e.w2c[wn + 32 + run * 8 + kh4];
    }

    // per-b2 scalar partial pair: p0 = row wm+l31, p1 = row wm+32+l31
#define EPI_PAIR(QROW, T0, T1) do {                                          \
        float _p0 = 0.f, _p1 = 0.f;                                          \
        _Pragma("unroll")                                                    \
        for (int run = 0; run < 4; ++run) {                                  \
            const float4 q0 = *(const float4*)((QROW) + wn + run * 8 + kh4); \
            const float4 q1 = *(const float4*)((QROW) + wn + 32 + run * 8 + kh4); \
            const float4 wA = wvA[run], wB = wvB[run];                       \
            _p0 += fmaxf(acc00[run * 4 + 0] + q0.x, 0.f) * wA.x;             \
            _p1 += fmaxf(acc01[run * 4 + 0] + q0.x, 0.f) * wA.x;             \
            _p0 += fmaxf(acc10[run * 4 + 0] + q1.x, 0.f) * wB.x;             \
            _p1 += fmaxf(acc11[run * 4 + 0] + q1.x, 0.f) * wB.x;             \
            _p0 += fmaxf(acc00[run * 4 + 1] + q0.y, 0.f) * wA.y;             \
            _p1 += fmaxf(acc01[run * 4 + 1] + q0.y, 0.f) * wA.y;             \
            _p0 += fmaxf(acc10[run * 4 + 1] + q1.y, 0.f) * wB.y;             \
            _p1 += fmaxf(acc11[run * 4 + 1] + q1.y, 0.f) * wB.y;             \
            _p0 += fmaxf(acc00[run * 4 + 2] + q0.z, 0.f) * wA.z;             \
            _p1 += fmaxf(acc01[run * 4 + 2] + q0.z, 0.f) * wA.z;             \
            _p0 += fmaxf(acc10[run * 4 + 2] + q1.z, 0.f) * wB.z;             \
            _p1 += fmaxf(acc11[run * 4 + 2] + q1.z, 0.f) * wB.z;             \
            _p0 += fmaxf(acc00[run * 4 + 3] + q0.w, 0.f) * wA.w;             \
            _p1 += fmaxf(acc01[run * 4 + 3] + q0.w, 0.f) * wA.w;             \
            _p0 += fmaxf(acc10[run * 4 + 3] + q1.w, 0.f) * wB.w;             \
            _p1 += fmaxf(acc11[run * 4 + 3] + q1.w, 0.f) * wB.w;             \
        }                                                                    \
        T0 = _p0 + __shfl_xor(_p0, 32);                                      \
        T1 = _p1 + __shfl_xor(_p1, 32);                                      \
    } while (0)

    if (is_dec) {
#pragma unroll
        for (int b2 = 0; b2 < 8; ++b2) {
            float t0, t1;
            EPI_PAIR(&u.e.qT[b2][0], t0, t1);
            if (kh == 0) {
                float* o = out + (size_t)b2 * OUTW + m0 + wm;
                unsafeAtomicAdd(o + l31, t0);
                unsafeAtomicAdd(o + 32 + l31, t1);
            }
        }
    } else {
        const int bfix = m0 >> 11;          // 128-row tile never crosses a batch
        float t0, t1;
        EPI_PAIR(&u.e.qT[bfix][0], t0, t1);
        if (kh == 0) {
            const int t0i = (m0 & 2047) + wm + l31;
            const int t1i = t0i + 32;
            const float mv0 = mask[bfix * Tdim + t0i];
            const float mv1 = mask[bfix * Tdim + t1i];
            float* o = out + (size_t)bfix * OUTW + Vdim;
            unsafeAtomicAdd(o + t0i, mv0 * t0);
            unsafeAtomicAdd(o + t1i, mv1 * t1);
        }
    }
#undef EPI_PAIR
}

extern "C" void kernel_launch(void* const* d_in, const int* in_sizes, int n_in,
                              void* d_out, int out_size, void* d_ws, size_t ws_size,
                              hipStream_t stream) {
    const float* input_embeds  = (const float*)d_in[0];  // (8,1,512)
    const float* target_embeds = (const float*)d_in[1];  // (8,2048,512)
    const float* input_mask    = (const float*)d_in[2];  // (8,2048)
    const float* w1            = (const float*)d_in[3];  // (512,1024)
    const float* b1            = (const float*)d_in[4];  // (512,)
    const float* w2            = (const float*)d_in[5];  // (512,)
    const float* decoder_w     = (const float*)d_in[6];  // (32000,512)
    float* out = (float*)d_out;

    // ws: qp 16 KB | wt bf16 512x512 (512 KB)
    float* qp = (float*)d_ws;
    unsigned short* wt = (unsigned short*)((char*)d_ws + 16384);

    prep_kernel<<<WT_BLOCKS + QP_BLOCKS + INIT_BLOCKS, 256, 0, stream>>>(
        w1, input_embeds, b1, input_mask, wt, qp, out);
    gemm_kernel<<<48 * 32, 256, 0, stream>>>(
        decoder_w, target_embeds, wt, qp, w2, input_mask, out);
}

// Round 12
// 172.814 us; speedup vs baseline: 1.0903x; 1.0903x over previous
//
#include <hip/hip_runtime.h>
#include <hip/hip_bf16.h>

// Shapes: B=8, Q=1, T=2048, H=512, V=32000
#define Hdim 512
#define Bdim 8
#define Tdim 2048
#define Vdim 32000
#define OUTW (Vdim + Tdim)        // 34048
#define DEC_TILES (Vdim / 128)    // 250
#define REP_TILES ((Bdim * Tdim) / 128)  // 128
#define NTILES (DEC_TILES + REP_TILES)   // 378

typedef __attribute__((ext_vector_type(8))) short short8;
typedef __attribute__((ext_vector_type(16))) float f32x16;

__device__ __forceinline__ unsigned packbf2(float a, float b) {
    __hip_bfloat162 h = __float22bfloat162_rn(make_float2(a, b));  // a -> low 16
    union { __hip_bfloat162 h; unsigned u; } c; c.h = h;
    return c.u;
}

union U8 { unsigned u[4]; short8 s; };
__device__ __forceinline__ short8 cvt8(const float4 f0, const float4 f1) {
    U8 r;
    r.u[0] = packbf2(f0.x, f0.y); r.u[1] = packbf2(f0.z, f0.w);
    r.u[2] = packbf2(f1.x, f1.y); r.u[3] = packbf2(f1.z, f1.w);
    return r.s;
}

// ---------------- prep: w1t -> bf16 [n][k] + qp + out-init (r1-verified) ------
#define WT_BLOCKS 128                  // 512x512 elems, 8 per thread
#define QP_BLOCKS (Bdim * Hdim / 4)    // 1024 blocks of 4 waves
#define INIT_BLOCKS (Bdim * OUTW / 4 / 256)   // 266: float4-init of out

__global__ __launch_bounds__(256) void prep_kernel(
    const float* __restrict__ w1, const float* __restrict__ x,
    const float* __restrict__ b1, const float* __restrict__ mask,
    unsigned short* __restrict__ wt, float* __restrict__ qp,
    float* __restrict__ out)
{
    const int bid = blockIdx.x;
    if (bid < WT_BLOCKS) {
        // wt[n][kk] = bf16(w1[n*1024 + 512 + kk])
        const int i = bid * 256 + threadIdx.x;   // 8-elem group index
        const int n = i >> 6;
        const int kk = (i & 63) * 8;
        const float4* s = (const float4*)(w1 + (size_t)n * 1024 + 512 + kk);
        const float4 v0 = s[0], v1 = s[1];
        uint4 o;
        o.x = packbf2(v0.x, v0.y); o.y = packbf2(v0.z, v0.w);
        o.z = packbf2(v1.x, v1.y); o.w = packbf2(v1.z, v1.w);
        ((uint4*)wt)[i] = o;
    } else if (bid < WT_BLOCKS + QP_BLOCKS) {
        // qp[b,k] = x[b,:].w1q[k,:] + b1[k], one wave per (b,k)
        const int widx = (bid - WT_BLOCKS) * 4 + (threadIdx.x >> 6);
        const int lane = threadIdx.x & 63;
        const int b = widx >> 9, k = widx & 511;
        const float4* xr = (const float4*)(x + b * Hdim);
        const float4* wr = (const float4*)(w1 + (size_t)k * 1024);
        float4 x0 = xr[lane * 2], x1 = xr[lane * 2 + 1];
        float4 w0 = wr[lane * 2], w1v = wr[lane * 2 + 1];
        float s = x0.x * w0.x + x0.y * w0.y + x0.z * w0.z + x0.w * w0.w
                + x1.x * w1v.x + x1.y * w1v.y + x1.z * w1v.z + x1.w * w1v.w;
#pragma unroll
        for (int off = 32; off > 0; off >>= 1) s += __shfl_down(s, off);
        if (lane == 0) qp[b * Hdim + k] = s + b1[k];
    } else {
        // out init: dec region = 0, rep region = -1000*(1-mask)  (gemm atomicAdds partials)
        const int idx4 = (bid - WT_BLOCKS - QP_BLOCKS) * 256 + threadIdx.x;  // float4 idx
        const int b = idx4 / (OUTW / 4);
        const int c4 = (idx4 - b * (OUTW / 4)) * 4;     // col within row, mult of 4
        float4 v;
        if (c4 < Vdim) {
            v = make_float4(0.f, 0.f, 0.f, 0.f);
        } else {
            const int t = c4 - Vdim;
            const float4 mv = *(const float4*)(mask + b * Tdim + t);
            v = make_float4(-1000.f * (1.f - mv.x), -1000.f * (1.f - mv.y),
                            -1000.f * (1.f - mv.z), -1000.f * (1.f - mv.w));
        }
        ((float4*)out)[idx4] = v;
    }
}

// ---------------- fused MFMA GEMM + atomic epilogue -> out --------------------
// Round-12 = round-10 verbatim (session best: 173.6us total, gemm 73.9us).
// Ledger of measured-worse neighbors: counted-vmcnt x2 (r6 race / r8 -30%),
// cooperative fusion (r9 correctness), bf16-A LDS x2 (r7 -20% / r11 -26%,
// conflicts 15x).  r10's glds-direct fp32-A + per-use cvt + single
// __syncthreads/step + atomic epilogue is the verified local optimum.
// Grid 1536 (48 groups x 32): mt = (b>>5)*8 + (b&7), chunk = (b>>3)&3 so the 4
// chunk-partners of one mt share blockIdx%8 (same XCD -> shared L2 A-tile).
// MFMA operands SWAPPED (mfma(W,A)): acc rows = n, acc cols = output row.
__global__ __launch_bounds__(256, 3) void gemm_kernel(
    const float* __restrict__ Adec,            // 32000 x 512 fp32 (original)
    const float* __restrict__ Atgt,            // 16384 x 512 fp32 (original)
    const unsigned short* __restrict__ Wt,     // 512 x 512 bf16 (w1t [n][k])
    const float* __restrict__ qp,              // 8 x 512 fp32
    const float* __restrict__ w2,              // 512 fp32
    const float* __restrict__ mask,            // 8 x 2048 fp32
    float* __restrict__ out)                   // 8 x 34048 fp32 (pre-initialized)
{
    // A: fp32, tile 128rows x 32k packed 2 rows/LDS-row: elem(row,k) at
    //    [row&63][(row>>6)*32 + k]; 16B-slot XOR swizzle phys = lc ^ (rr&15).
    // W: bf16, tile 128n x 32k packed: [n&63][(n>>6)*32 + k]; 8 slots/row,
    //    phys = lc ^ (rr&7).
    // e: epilogue overlay (qp^T chunk [b][n] + w2 chunk), staged after K-loop.
    __shared__ union {
        struct { float A[2][64][64]; unsigned short W[2][64][64]; } g;  // 32+16 KB
        struct { float qT[8][128]; float w2c[128]; } e;
    } u;

    const int tid  = threadIdx.x;
    const int lane = tid & 63;
    const int w    = tid >> 6;

    const int b = blockIdx.x;
    const int mt = (b >> 5) * 8 + (b & 7);
    if (mt >= NTILES) return;
    const int chunk = (b >> 3) & 3;
    const int n0 = chunk << 7;
    const bool is_dec = (mt < DEC_TILES);
    const int m0 = (is_dec ? mt : mt - DEC_TILES) << 7;
    const float* __restrict__ Af = is_dec ? Adec : Atgt;

    // ---- staging pointers (pre-swizzled global source, linear LDS dest) ----
    // A: 16 instrs of 1KB (4 LDS-rows each); instr i = w*4+j; lane l -> LDS-row
    // rr = i*4 + (l>>4), slot l&15.  Slot holds logical chunk lc = (l&15)^(rr&15)
    // -> global (row m0 + rr + 64*(lc>>3), k (lc&7)*4).
    const float* gAp[4];
#pragma unroll
    for (int j = 0; j < 4; ++j) {
        const int rr = w * 16 + j * 4 + (lane >> 4);
        const int lc = (lane & 15) ^ (rr & 15);
        gAp[j] = Af + (size_t)(m0 + rr + 64 * (lc >> 3)) * 512 + (lc & 7) * 4;
    }
    // W: 8 instrs of 1KB (8 LDS-rows each); instr i = w*2+j; lane l -> LDS-row
    // rr = i*8 + (l>>3), slot l&7.  lc = (l&7)^(l>>3) (rr&7 == l>>3).
    const unsigned short* gWp[2];
    {
        const int lcw = (lane & 7) ^ (lane >> 3);
#pragma unroll
        for (int j = 0; j < 2; ++j) {
            const int rr = w * 16 + j * 8 + (lane >> 3);
            gWp[j] = Wt + (size_t)(n0 + rr + 64 * (lcw >> 2)) * 512 + (lcw & 3) * 8;
        }
    }

#define STAGE(bb, koff) do {                                                  \
        _Pragma("unroll")                                                     \
        for (int j = 0; j < 4; ++j)                                           \
            __builtin_amdgcn_global_load_lds(                                 \
                (const __attribute__((address_space(1))) unsigned int*)(gAp[j] + (koff)), \
                (__attribute__((address_space(3))) unsigned int*)(&u.g.A[bb][w * 16 + j * 4][0]), \
                16, 0, 0);                                                    \
        _Pragma("unroll")                                                     \
        for (int j = 0; j < 2; ++j)                                           \
            __builtin_amdgcn_global_load_lds(                                 \
                (const __attribute__((address_space(1))) unsigned int*)(gWp[j] + (koff)), \
                (__attribute__((address_space(3))) unsigned int*)(&u.g.W[bb][w * 16 + j * 8][0]), \
                16, 0, 0);                                                    \
    } while (0)

    f32x16 acc00, acc01, acc10, acc11;
#pragma unroll
    for (int i = 0; i < 16; ++i) { acc00[i] = 0.f; acc01[i] = 0.f; acc10[i] = 0.f; acc11[i] = 0.f; }

    const int wm  = (w & 1) << 6;     // output-row offset of this wave
    const int wn  = (w >> 1) << 6;    // n offset of this wave (within chunk)
    const int l31 = lane & 31;
    const int kh  = lane >> 5;
    const int rx15 = l31 & 15;        // (rr&15) for A reads (rows l31 / l31+32)
    const int rx7  = l31 & 7;         // (rr&7)  for W reads
    const int ha  = wm >> 6;          // A row-half (packed dim)
    const int hw  = wn >> 6;          // W n-half (packed dim)

    // prologue: stage tile 0 into buf 0
    STAGE(0, 0);
    __syncthreads();

    int cur = 0;
    for (int t = 0; t < 16; ++t) {
        if (t < 15) STAGE(cur ^ 1, (t + 1) * 32);   // prefetch next tile
        const float (* __restrict__ Ab)[64] = u.g.A[cur];
        const unsigned short (* __restrict__ Wb)[64] = u.g.W[cur];
#pragma unroll
        for (int s = 0; s < 2; ++s) {
            const int g  = s * 2 + kh;                 // k-group 0..3 (8 bf16 each)
            const int p0 = ((ha * 8 + 2 * g) ^ rx15) << 2;      // float offset
            const int p1 = ((ha * 8 + 2 * g + 1) ^ rx15) << 2;
            const float4 a0f0 = *(const float4*)&Ab[l31][p0];
            const float4 a0f1 = *(const float4*)&Ab[l31][p1];
            const float4 a1f0 = *(const float4*)&Ab[l31 + 32][p0];
            const float4 a1f1 = *(const float4*)&Ab[l31 + 32][p1];
            const short8 a0 = cvt8(a0f0, a0f1);
            const short8 a1 = cvt8(a1f0, a1f1);
            const int ow = ((hw * 4 + g) ^ rx7) << 3;           // W elem offset
            const short8 b0 = *(const short8*)&Wb[l31][ow];
            const short8 b1 = *(const short8*)&Wb[l31 + 32][ow];
            // SWAPPED operands: D rows = n (W index), D cols = output row (A index)
            acc00 = __builtin_amdgcn_mfma_f32_32x32x16_bf16(b0, a0, acc00, 0, 0, 0);
            acc01 = __builtin_amdgcn_mfma_f32_32x32x16_bf16(b0, a1, acc01, 0, 0, 0);
            acc10 = __builtin_amdgcn_mfma_f32_32x32x16_bf16(b1, a0, acc10, 0, 0, 0);
            acc11 = __builtin_amdgcn_mfma_f32_32x32x16_bf16(b1, a1, acc11, 0, 0, 0);
        }
        __syncthreads();   // drains prefetch (vmcnt 0) + all readers done
        cur ^= 1;
    }
#undef STAGE

    // ---------------- fused epilogue (atomic, r1/r10-verified pattern) ------
    // acc{X}{Y}[r]: n = wn + 32*X + ra2(r,kh), vrow = wm + 32*Y + l31
    // with r = run*4 + j: ra2 = j + 8*run + 4*kh  -> n runs are float4-contiguous.
    // (C/D layout verified m74/m101: col=lane&31, row=(r&3)+8*(r>>2)+4*(lane>>5))
    {
        const int qb = tid >> 5;              // 0..7
        const int qn = (tid & 31) << 2;       // 0..124
        *(float4*)&u.e.qT[qb][qn] = *(const float4*)&qp[qb * Hdim + n0 + qn];
        if (tid < 32) *(float4*)&u.e.w2c[tid << 2] = *(const float4*)&w2[n0 + (tid << 2)];
    }
    __syncthreads();

    const int kh4 = kh << 2;

    // w2 fragments in regs (statically indexed -> 8 float4 = 32 VGPRs)
    float4 wvA[4], wvB[4];
#pragma unroll
    for (int run = 0; run < 4; ++run) {
        wvA[run] = *(const float4*)&u.e.w2c[wn + run * 8 + kh4];
        wvB[run] = *(const float4*)&u.e.w2c[wn + 32 + run * 8 + kh4];
    }

    // per-b2 scalar partial pair: p0 = row wm+l31, p1 = row wm+32+l31
#define EPI_PAIR(QROW, T0, T1) do {                                          \
        float _p0 = 0.f, _p1 = 0.f;                                          \
        _Pragma("unroll")                                                    \
        for (int run = 0; run < 4; ++run) {                                  \
            const float4 q0 = *(const float4*)((QROW) + wn + run * 8 + kh4); \
            const float4 q1 = *(const float4*)((QROW) + wn + 32 + run * 8 + kh4); \
            const float4 wA = wvA[run], wB = wvB[run];                       \
            _p0 += fmaxf(acc00[run * 4 + 0] + q0.x, 0.f) * wA.x;             \
            _p1 += fmaxf(acc01[run * 4 + 0] + q0.x, 0.f) * wA.x;             \
            _p0 += fmaxf(acc10[run * 4 + 0] + q1.x, 0.f) * wB.x;             \
            _p1 += fmaxf(acc11[run * 4 + 0] + q1.x, 0.f) * wB.x;             \
            _p0 += fmaxf(acc00[run * 4 + 1] + q0.y, 0.f) * wA.y;             \
            _p1 += fmaxf(acc01[run * 4 + 1] + q0.y, 0.f) * wA.y;             \
            _p0 += fmaxf(acc10[run * 4 + 1] + q1.y, 0.f) * wB.y;             \
            _p1 += fmaxf(acc11[run * 4 + 1] + q1.y, 0.f) * wB.y;             \
            _p0 += fmaxf(acc00[run * 4 + 2] + q0.z, 0.f) * wA.z;             \
            _p1 += fmaxf(acc01[run * 4 + 2] + q0.z, 0.f) * wA.z;             \
            _p0 += fmaxf(acc10[run * 4 + 2] + q1.z, 0.f) * wB.z;             \
            _p1 += fmaxf(acc11[run * 4 + 2] + q1.z, 0.f) * wB.z;             \
            _p0 += fmaxf(acc00[run * 4 + 3] + q0.w, 0.f) * wA.w;             \
            _p1 += fmaxf(acc01[run * 4 + 3] + q0.w, 0.f) * wA.w;             \
            _p0 += fmaxf(acc10[run * 4 + 3] + q1.w, 0.f) * wB.w;             \
            _p1 += fmaxf(acc11[run * 4 + 3] + q1.w, 0.f) * wB.w;             \
        }                                                                    \
        T0 = _p0 + __shfl_xor(_p0, 32);                                      \
        T1 = _p1 + __shfl_xor(_p1, 32);                                      \
    } while (0)

    if (is_dec) {
#pragma unroll
        for (int b2 = 0; b2 < 8; ++b2) {
            float t0, t1;
            EPI_PAIR(&u.e.qT[b2][0], t0, t1);
            if (kh == 0) {
                float* o = out + (size_t)b2 * OUTW + m0 + wm;
                unsafeAtomicAdd(o + l31, t0);
                unsafeAtomicAdd(o + 32 + l31, t1);
            }
        }
    } else {
        const int bfix = m0 >> 11;          // 128-row tile never crosses a batch
        float t0, t1;
        EPI_PAIR(&u.e.qT[bfix][0], t0, t1);
        if (kh == 0) {
            const int t0i = (m0 & 2047) + wm + l31;
            const int t1i = t0i + 32;
            const float mv0 = mask[bfix * Tdim + t0i];
            const float mv1 = mask[bfix * Tdim + t1i];
            float* o = out + (size_t)bfix * OUTW + Vdim;
            unsafeAtomicAdd(o + t0i, mv0 * t0);
            unsafeAtomicAdd(o + t1i, mv1 * t1);
        }
    }
#undef EPI_PAIR
}

extern "C" void kernel_launch(void* const* d_in, const int* in_sizes, int n_in,
                              void* d_out, int out_size, void* d_ws, size_t ws_size,
                              hipStream_t stream) {
    const float* input_embeds  = (const float*)d_in[0];  // (8,1,512)
    const float* target_embeds = (const float*)d_in[1];  // (8,2048,512)
    const float* input_mask    = (const float*)d_in[2];  // (8,2048)
    const float* w1            = (const float*)d_in[3];  // (512,1024)
    const float* b1            = (const float*)d_in[4];  // (512,)
    const float* w2            = (const float*)d_in[5];  // (512,)
    const float* decoder_w     = (const float*)d_in[6];  // (32000,512)
    float* out = (float*)d_out;

    // ws: qp 16 KB | wt bf16 512x512 (512 KB)
    float* qp = (float*)d_ws;
    unsigned short* wt = (unsigned short*)((char*)d_ws + 16384);

    prep_kernel<<<WT_BLOCKS + QP_BLOCKS + INIT_BLOCKS, 256, 0, stream>>>(
        w1, input_embeds, b1, input_mask, wt, qp, out);
    gemm_kernel<<<48 * 32, 256, 0, stream>>>(
        decoder_w, target_embeds, wt, qp, w2, input_mask, out);
}